// Round 2
// baseline (1015.298 us; speedup 1.0000x reference)
//
#include <hip/hip_runtime.h>
#include <stdint.h>

#define N_ROWS 131072
#define DIM 64
#define K_CODES 1024

// ---------------- kernel 1: per-code squared norms into d_ws ----------------
__global__ __launch_bounds__(256) void sumc2_kernel(const float* __restrict__ cb,
                                                    float* __restrict__ sumc2) {
    int k = blockIdx.x * 256 + threadIdx.x;
    if (k < K_CODES) {
        const float* r = cb + k * DIM;
        float s = 0.f;
        #pragma unroll
        for (int j = 0; j < DIM; ++j) s = fmaf(r[j], r[j], s);
        sumc2[k] = s;
    }
}

// ---------------- threefry2x32 (JAX-compatible, key = (0,42)) ----------------
__device__ __forceinline__ uint32_t rotl32(uint32_t x, uint32_t r) {
    return (x << r) | (x >> (32u - r));
}
__device__ __forceinline__ void tf_round(uint32_t& x0, uint32_t& x1, uint32_t r) {
    x0 += x1; x1 = rotl32(x1, r); x1 ^= x0;
}
__device__ __forceinline__ void threefry2x32_k42(uint32_t c0, uint32_t c1,
                                                 uint32_t& o0, uint32_t& o1) {
    const uint32_t ks0 = 0u, ks1 = 42u, ks2 = 0x1BD11BDAu ^ 0u ^ 42u;
    uint32_t x0 = c0 + ks0, x1 = c1 + ks1;
    tf_round(x0,x1,13); tf_round(x0,x1,15); tf_round(x0,x1,26); tf_round(x0,x1,6);
    x0 += ks1; x1 += ks2 + 1u;
    tf_round(x0,x1,17); tf_round(x0,x1,29); tf_round(x0,x1,16); tf_round(x0,x1,24);
    x0 += ks2; x1 += ks0 + 2u;
    tf_round(x0,x1,13); tf_round(x0,x1,15); tf_round(x0,x1,26); tf_round(x0,x1,6);
    x0 += ks0; x1 += ks1 + 3u;
    tf_round(x0,x1,17); tf_round(x0,x1,29); tf_round(x0,x1,16); tf_round(x0,x1,24);
    x0 += ks1; x1 += ks2 + 4u;
    tf_round(x0,x1,13); tf_round(x0,x1,15); tf_round(x0,x1,26); tf_round(x0,x1,6);
    x0 += ks2; x1 += ks0 + 5u;
    o0 = x0; o1 = x1;
}

// g = -log(-log(u)); u = max(tiny, bits-derived uniform in [0,1)).
// Inner log via log1p poly for u>0.9375 (hw __logf abs-err near 1 would wreck
// the tiny -log(u)); outer log only needs absolute accuracy -> __logf is fine.
__device__ __forceinline__ float gumbel_from_bits(uint32_t bits) {
    uint32_t fb = (bits >> 9) | 0x3f800000u;
    float f = __uint_as_float(fb) - 1.0f;          // [0,1), exact
    float u = fmaxf(1.17549435e-38f, f);           // == max(tiny, f*(1-tiny)+tiny) in f32
    float w = u - 1.0f;                            // exact for u in [0.5,1]
    float p = fmaf(w, 0.2f, -0.25f);
    p = fmaf(w, p, 0.33333333333f);
    p = fmaf(w, p, -0.5f);
    p = fmaf(w, p, 1.0f);
    float v_poly = -(w * p);                       // -log1p(w), |w|<=1/16
    float v_log  = -__logf(u);
    float v = (u > 0.9375f) ? v_poly : v_log;
    return -__logf(v);
}

// ---------------- kernel 2: fused dist + argmin + online gumbel-softmax + emb ----------------
__global__ __launch_bounds__(256) void quant_kernel(
    const float* __restrict__ x, const float* __restrict__ cb,
    const float* __restrict__ temp, const float* __restrict__ sumc2,
    float* __restrict__ out_emb, float* __restrict__ out_ids)
{
    const int lane = threadIdx.x & 63;
    const int gw   = blockIdx.x * 4 + (threadIdx.x >> 6);
    const int n    = gw * 64 + lane;               // lane owns row n
    const float invT = 1.0f / temp[0];

    // row of x into VGPRs
    float xr[DIM];
    const float4* xrow = reinterpret_cast<const float4*>(x + (size_t)n * DIM);
    #pragma unroll
    for (int j4 = 0; j4 < DIM/4; ++j4) {
        float4 v = xrow[j4];
        xr[4*j4+0]=v.x; xr[4*j4+1]=v.y; xr[4*j4+2]=v.z; xr[4*j4+3]=v.w;
    }
    float sumx2 = 0.f;
    #pragma unroll
    for (int j = 0; j < DIM; ++j) sumx2 = fmaf(xr[j], xr[j], sumx2);

    // JAX threefry counter layout: i = n*1024+k; n<65536 -> word0 of (i, i+2^26),
    // else word1 of (i-2^26, i). Wave-uniform branch (64-row blocks).
    const bool hi = (n >= 65536);
    uint32_t cbase = (uint32_t)n * 1024u;
    if (hi) cbase -= (1u << 26);

    float m = -3.4e38f, Z = 0.f;
    float emb[DIM];
    #pragma unroll
    for (int j = 0; j < DIM; ++j) emb[j] = 0.f;

    // top-2 argmin tracking (f32); exact f64 tie-break after the loop
    float dmin1 = 3.4e38f, dmin2 = 3.4e38f;
    int   kmin1 = 0,       kmin2 = 0;

    for (int k = 0; k < K_CODES; ++k) {
        uint32_t o0, o1;
        threefry2x32_k42(cbase + (uint32_t)k, cbase + (uint32_t)k + (1u << 26), o0, o1);
        float g = gumbel_from_bits(hi ? o1 : o0);

        // wave-uniform codebook row -> scalar loads (SGPRs), shared by all lanes
        const float* crow = cb + (k << 6);
        float cr[DIM];
        #pragma unroll
        for (int j = 0; j < DIM; ++j) cr[j] = crow[j];

        float dot = 0.f;
        #pragma unroll
        for (int j = 0; j < DIM; ++j) dot = fmaf(cr[j], xr[j], dot);

        float dist = (sumx2 + sumc2[k]) - 2.0f * dot;

        // strict < keeps first occurrence (numpy argmax semantics)
        if (dist < dmin1)      { dmin2 = dmin1; kmin2 = kmin1; dmin1 = dist; kmin1 = k; }
        else if (dist < dmin2) { dmin2 = dist; kmin2 = k; }

        float l = (g - dist) * invT;
        if (l > m) {                                    // rare path (~24% of iters wave-wide)
            float scale = __expf(m - l);
            m = l;
            Z = fmaf(Z, scale, 1.0f);
            #pragma unroll
            for (int j = 0; j < DIM; ++j) emb[j] = fmaf(emb[j], scale, cr[j]);
        } else {
            float p = __expf(l - m);
            Z += p;
            #pragma unroll
            for (int j = 0; j < DIM; ++j) emb[j] = fmaf(cr[j], p, emb[j]);
        }
    }

    // Exact refinement when f32 top-2 gap is within 1e-2 (>>300x worst-case
    // per-k-varying f32 error ~3e-5; row-constant sumx2 error cancels in argmin).
    if (dmin2 - dmin1 < 1e-2f) {
        double sx2 = 0.0;
        #pragma unroll
        for (int j = 0; j < DIM; ++j) sx2 = fma((double)xr[j], (double)xr[j], sx2);
        double dd[2];
        int    kk[2] = {kmin1, kmin2};
        for (int c = 0; c < 2; ++c) {
            const float* crow = cb + (kk[c] << 6);
            double dot = 0.0, c2 = 0.0;
            #pragma unroll
            for (int j = 0; j < DIM; ++j) {
                double cj = (double)crow[j];
                c2  = fma(cj, cj, c2);
                dot = fma((double)xr[j], cj, dot);
            }
            dd[c] = sx2 + c2 - 2.0 * dot;
        }
        if (dd[1] < dd[0] || (dd[1] == dd[0] && kmin2 < kmin1)) kmin1 = kmin2;
    }

    float rZ = 1.0f / Z;
    float4* orow = reinterpret_cast<float4*>(out_emb + (size_t)n * DIM);
    #pragma unroll
    for (int j4 = 0; j4 < DIM/4; ++j4) {
        float4 v;
        v.x = emb[4*j4+0]*rZ; v.y = emb[4*j4+1]*rZ;
        v.z = emb[4*j4+2]*rZ; v.w = emb[4*j4+3]*rZ;
        orow[j4] = v;
    }
    out_ids[n] = (float)kmin1;   // harness reads d_out as f32; ids <= 1023 exact in f32
}

extern "C" void kernel_launch(void* const* d_in, const int* in_sizes, int n_in,
                              void* d_out, int out_size, void* d_ws, size_t ws_size,
                              hipStream_t stream) {
    const float* x    = (const float*)d_in[0];
    const float* cb   = (const float*)d_in[1];
    const float* temp = (const float*)d_in[2];
    float* sumc2      = (float*)d_ws;                  // 1024 floats of scratch
    float* out_emb    = (float*)d_out;
    float* out_ids    = (float*)d_out + (size_t)N_ROWS * DIM;

    sumc2_kernel<<<(K_CODES + 255) / 256, 256, 0, stream>>>(cb, sumc2);
    quant_kernel<<<N_ROWS / 256, 256, 0, stream>>>(x, cb, temp, sumc2, out_emb, out_ids);
}

// Round 3
// 638.364 us; speedup vs baseline: 1.5905x; 1.5905x over previous
//
#include <hip/hip_runtime.h>
#include <stdint.h>

#define N_ROWS 131072
#define DIM 64
#define K_CODES 1024

typedef __attribute__((ext_vector_type(8))) short short8;
typedef __attribute__((ext_vector_type(4))) float float4v;

// ---------------- bf16 split helpers ----------------
__device__ __forceinline__ uint16_t f2bf(float f) {          // RTNE
    uint32_t u = __float_as_uint(f);
    u += 0x7fffu + ((u >> 16) & 1u);
    return (uint16_t)(u >> 16);
}
__device__ __forceinline__ float bf2f(uint16_t h) {
    return __uint_as_float(((uint32_t)h) << 16);
}

// ---------------- kernel 1: per-code squared norms into d_ws ----------------
__global__ __launch_bounds__(256) void sumc2_kernel(const float* __restrict__ cb,
                                                    float* __restrict__ sumc2) {
    int k = blockIdx.x * 256 + threadIdx.x;
    if (k < K_CODES) {
        const float* r = cb + k * DIM;
        float s = 0.f;
        #pragma unroll
        for (int j = 0; j < DIM; ++j) s = fmaf(r[j], r[j], s);
        sumc2[k] = s;
    }
}

// ---------------- threefry2x32 (JAX-compatible, key = (0,42)) ----------------
__device__ __forceinline__ uint32_t rotl32(uint32_t x, uint32_t r) {
    return (x << r) | (x >> (32u - r));
}
__device__ __forceinline__ void tf_round(uint32_t& x0, uint32_t& x1, uint32_t r) {
    x0 += x1; x1 = rotl32(x1, r); x1 ^= x0;
}
__device__ __forceinline__ void threefry2x32_k42(uint32_t c0, uint32_t c1,
                                                 uint32_t& o0, uint32_t& o1) {
    const uint32_t ks0 = 0u, ks1 = 42u, ks2 = 0x1BD11BDAu ^ 0u ^ 42u;
    uint32_t x0 = c0 + ks0, x1 = c1 + ks1;
    tf_round(x0,x1,13); tf_round(x0,x1,15); tf_round(x0,x1,26); tf_round(x0,x1,6);
    x0 += ks1; x1 += ks2 + 1u;
    tf_round(x0,x1,17); tf_round(x0,x1,29); tf_round(x0,x1,16); tf_round(x0,x1,24);
    x0 += ks2; x1 += ks0 + 2u;
    tf_round(x0,x1,13); tf_round(x0,x1,15); tf_round(x0,x1,26); tf_round(x0,x1,6);
    x0 += ks0; x1 += ks1 + 3u;
    tf_round(x0,x1,17); tf_round(x0,x1,29); tf_round(x0,x1,16); tf_round(x0,x1,24);
    x0 += ks1; x1 += ks2 + 4u;
    tf_round(x0,x1,13); tf_round(x0,x1,15); tf_round(x0,x1,26); tf_round(x0,x1,6);
    x0 += ks2; x1 += ks0 + 5u;
    o0 = x0; o1 = x1;
}

__device__ __forceinline__ float gumbel_from_bits(uint32_t bits) {
    uint32_t fb = (bits >> 9) | 0x3f800000u;
    float f = __uint_as_float(fb) - 1.0f;
    float u = fmaxf(1.17549435e-38f, f);
    float w = u - 1.0f;
    float p = fmaf(w, 0.2f, -0.25f);
    p = fmaf(w, p, 0.33333333333f);
    p = fmaf(w, p, -0.5f);
    p = fmaf(w, p, 1.0f);
    float v_poly = -(w * p);
    float v_log  = -__logf(u);
    float v = (u > 0.9375f) ? v_poly : v_log;
    return -__logf(v);
}

// top-2 insert, strict < (first-occurrence tie-break; k processed ascending per lane)
__device__ __forceinline__ void top2_ins(float d, int k, float& d1, int& k1, float& d2, int& k2) {
    if (d < d1)      { d2 = d1; k2 = k1; d1 = d; k1 = k; }
    else if (d < d2) { d2 = d; k2 = k; }
}

// ---------------- kernel 2: flash-style fused MFMA quantizer ----------------
// Grid: 2048 blocks x 256 threads. Block handles rows [32B, 32B+32) U [+65536,..).
// Wave w: 16 tile-rows t: row(t) = base + w*8 + (t>>1) + (t&1)*65536.
// Pairing: lane reg j rows {n0,n0+2^16,n1,n1+2^16} -> 2 threefry calls serve 4 gumbels.
__global__ __launch_bounds__(256) void quant_kernel(
    const float* __restrict__ x, const float* __restrict__ cb,
    const float* __restrict__ temp, const float* __restrict__ sumc2g,
    float* __restrict__ out_emb, float* __restrict__ out_ids)
{
    __shared__ __align__(16) uint16_t xhi[4][16][72];   // [wave][t][dim], pad->72
    __shared__ __align__(16) uint16_t xlo[4][16][72];
    __shared__ __align__(16) uint16_t cbhi[32][72];     // [code][dim]
    __shared__ __align__(16) uint16_t cblo[32][72];
    __shared__ __align__(16) uint16_t cbT [64][32];     // [dim][code] (hi only)
    __shared__ __align__(16) uint16_t pbuf[4][16][32];  // [wave][t][code_local]
    __shared__ float xpart[4][16][4];

    const int tid  = threadIdx.x;
    const int wave = tid >> 6;
    const int lane = tid & 63;
    const int quad = lane >> 4;
    const int col  = lane & 15;
    const float invT = 1.0f / temp[0];
    const int rowbase = blockIdx.x * 32 + wave * 8;     // low-row base for this wave

    // ---- stage X tile (once) + sumx2 partials ----
    {
        const int s = tid >> 2, w = s >> 4, t = s & 15, dq = tid & 3;
        const int row = blockIdx.x * 32 + w * 8 + (t >> 1) + ((t & 1) << 16);
        const float4* src = reinterpret_cast<const float4*>(x + (size_t)row * DIM + dq * 16);
        float v[16];
        #pragma unroll
        for (int i = 0; i < 4; ++i) {
            float4 f4 = src[i];
            v[4*i+0]=f4.x; v[4*i+1]=f4.y; v[4*i+2]=f4.z; v[4*i+3]=f4.w;
        }
        float ps = 0.f;
        short8 hv0, hv1, lv0, lv1;
        #pragma unroll
        for (int e = 0; e < 16; ++e) {
            ps = fmaf(v[e], v[e], ps);
            uint16_t h = f2bf(v[e]);
            uint16_t l = f2bf(v[e] - bf2f(h));
            if (e < 8) { hv0[e]   = (short)h; lv0[e]   = (short)l; }
            else       { hv1[e-8] = (short)h; lv1[e-8] = (short)l; }
        }
        *(short8*)&xhi[w][t][dq*16]   = hv0;
        *(short8*)&xhi[w][t][dq*16+8] = hv1;
        *(short8*)&xlo[w][t][dq*16]   = lv0;
        *(short8*)&xlo[w][t][dq*16+8] = lv1;
        xpart[w][t][dq] = ps;
    }
    __syncthreads();

    // A-frags (cached for whole kernel): A[m=lane&15][k=quad*8+j]
    const short8 ahi0 = *(const short8*)&xhi[wave][col][quad*8];
    const short8 ahi1 = *(const short8*)&xhi[wave][col][32 + quad*8];
    const short8 alo0 = *(const short8*)&xlo[wave][col][quad*8];
    const short8 alo1 = *(const short8*)&xlo[wave][col][32 + quad*8];

    float sxr[4];
    #pragma unroll
    for (int j = 0; j < 4; ++j) {
        int t = quad*4 + j;
        sxr[j] = (xpart[wave][t][0] + xpart[wave][t][1]) +
                 (xpart[wave][t][2] + xpart[wave][t][3]);
    }

    float m[4]  = {-3.0e38f, -3.0e38f, -3.0e38f, -3.0e38f};
    float Zp[4] = {0.f, 0.f, 0.f, 0.f};
    float4v e0 = {0,0,0,0}, e1 = {0,0,0,0}, e2 = {0,0,0,0}, e3 = {0,0,0,0};
    float d1[4] = {3.4e38f,3.4e38f,3.4e38f,3.4e38f};
    float d2[4] = {3.4e38f,3.4e38f,3.4e38f,3.4e38f};
    int   k1[4] = {0,0,0,0}, k2[4] = {0,0,0,0};

    const uint32_t n0 = (uint32_t)(rowbase + 2*quad);   // < 65536 always
    const uint32_t n1 = n0 + 1u;

    for (int blk = 0; blk < 32; ++blk) {
        __syncthreads();                                // prior reads done before overwrite
        const int kb = blk * 32;
        // ---- stage cb tile: 32 codes x 64 dims, hi/lo + transposed-hi ----
        {
            const int code = tid & 31, db = (tid >> 5) * 8;
            const float4* src = reinterpret_cast<const float4*>(cb + (size_t)(kb + code) * DIM + db);
            float4 a = src[0], b = src[1];
            float v[8] = {a.x,a.y,a.z,a.w,b.x,b.y,b.z,b.w};
            short8 hv, lv;
            uint16_t hh[8];
            #pragma unroll
            for (int e = 0; e < 8; ++e) {
                uint16_t h = f2bf(v[e]);
                uint16_t l = f2bf(v[e] - bf2f(h));
                hh[e] = h; hv[e] = (short)h; lv[e] = (short)l;
            }
            *(short8*)&cbhi[code][db] = hv;
            *(short8*)&cblo[code][db] = lv;
            #pragma unroll
            for (int e = 0; e < 8; ++e) cbT[db + e][code] = hh[e];
        }
        __syncthreads();

        // ---- GEMM1: S = X . CB^T  (split-bf16, 3 passes, 2 k-chunks) ----
        float4v S0 = {0,0,0,0}, S1 = {0,0,0,0};
        {
            const short8 bh0 = *(const short8*)&cbhi[col][quad*8];
            const short8 bh1 = *(const short8*)&cbhi[col][32 + quad*8];
            const short8 bl0 = *(const short8*)&cblo[col][quad*8];
            const short8 bl1 = *(const short8*)&cblo[col][32 + quad*8];
            S0 = __builtin_amdgcn_mfma_f32_16x16x32_bf16(ahi0, bh0, S0, 0,0,0);
            S0 = __builtin_amdgcn_mfma_f32_16x16x32_bf16(ahi1, bh1, S0, 0,0,0);
            S0 = __builtin_amdgcn_mfma_f32_16x16x32_bf16(ahi0, bl0, S0, 0,0,0);
            S0 = __builtin_amdgcn_mfma_f32_16x16x32_bf16(ahi1, bl1, S0, 0,0,0);
            S0 = __builtin_amdgcn_mfma_f32_16x16x32_bf16(alo0, bh0, S0, 0,0,0);
            S0 = __builtin_amdgcn_mfma_f32_16x16x32_bf16(alo1, bh1, S0, 0,0,0);
        }
        {
            const short8 bh0 = *(const short8*)&cbhi[16+col][quad*8];
            const short8 bh1 = *(const short8*)&cbhi[16+col][32 + quad*8];
            const short8 bl0 = *(const short8*)&cblo[16+col][quad*8];
            const short8 bl1 = *(const short8*)&cblo[16+col][32 + quad*8];
            S1 = __builtin_amdgcn_mfma_f32_16x16x32_bf16(ahi0, bh0, S1, 0,0,0);
            S1 = __builtin_amdgcn_mfma_f32_16x16x32_bf16(ahi1, bh1, S1, 0,0,0);
            S1 = __builtin_amdgcn_mfma_f32_16x16x32_bf16(ahi0, bl0, S1, 0,0,0);
            S1 = __builtin_amdgcn_mfma_f32_16x16x32_bf16(ahi1, bl1, S1, 0,0,0);
            S1 = __builtin_amdgcn_mfma_f32_16x16x32_bf16(alo0, bh0, S1, 0,0,0);
            S1 = __builtin_amdgcn_mfma_f32_16x16x32_bf16(alo1, bh1, S1, 0,0,0);
        }

        // ---- gumbels (paired threefry: 2 calls per tile serve 4 regs) ----
        const int kc0 = kb + col, kc1 = kb + 16 + col;
        float g0[4], g1[4];
        {
            uint32_t o0, o1, c;
            c = n0 * 1024u + (uint32_t)kc0;
            threefry2x32_k42(c, c + (1u << 26), o0, o1);
            g0[0] = gumbel_from_bits(o0); g0[1] = gumbel_from_bits(o1);
            c = n1 * 1024u + (uint32_t)kc0;
            threefry2x32_k42(c, c + (1u << 26), o0, o1);
            g0[2] = gumbel_from_bits(o0); g0[3] = gumbel_from_bits(o1);
            c = n0 * 1024u + (uint32_t)kc1;
            threefry2x32_k42(c, c + (1u << 26), o0, o1);
            g1[0] = gumbel_from_bits(o0); g1[1] = gumbel_from_bits(o1);
            c = n1 * 1024u + (uint32_t)kc1;
            threefry2x32_k42(c, c + (1u << 26), o0, o1);
            g1[2] = gumbel_from_bits(o0); g1[3] = gumbel_from_bits(o1);
        }

        const float sc0 = sumc2g[kc0], sc1 = sumc2g[kc1];
        float l0[4], l1[4], mn[4];
        #pragma unroll
        for (int j = 0; j < 4; ++j) {
            float dist0 = (sxr[j] + sc0) - 2.0f * S0[j];
            float dist1 = (sxr[j] + sc1) - 2.0f * S1[j];
            top2_ins(dist0, kc0, d1[j], k1[j], d2[j], k2[j]);
            top2_ins(dist1, kc1, d1[j], k1[j], d2[j], k2[j]);
            l0[j] = (g0[j] - dist0) * invT;
            l1[j] = (g1[j] - dist1) * invT;
            mn[j] = fmaxf(m[j], fmaxf(l0[j], l1[j]));
        }
        // row-max sync across the 16 lanes sharing this quad's rows
        #pragma unroll
        for (int mask = 1; mask < 16; mask <<= 1) {
            #pragma unroll
            for (int j = 0; j < 4; ++j) mn[j] = fmaxf(mn[j], __shfl_xor(mn[j], mask));
        }
        float4v av;
        #pragma unroll
        for (int j = 0; j < 4; ++j) {
            float alpha = __expf(m[j] - mn[j]);
            m[j] = mn[j];
            av[j] = alpha;
            float p0 = __expf(l0[j] - mn[j]);
            float p1 = __expf(l1[j] - mn[j]);
            Zp[j] = fmaf(Zp[j], alpha, p0 + p1);
            pbuf[wave][quad*4 + j][col]      = f2bf(p0);
            pbuf[wave][quad*4 + j][16 + col] = f2bf(p1);
        }
        e0 *= av; e1 *= av; e2 *= av; e3 *= av;
        __syncthreads();                                // pbuf visible (cross-lane)

        // ---- GEMM2: emb += P . CB  (A=P[t][code], B=cbT[dim][code]) ----
        const short8 pa  = *(const short8*)&pbuf[wave][col][quad*8];
        const short8 bt0 = *(const short8*)&cbT[col][quad*8];
        const short8 bt1 = *(const short8*)&cbT[16 + col][quad*8];
        const short8 bt2 = *(const short8*)&cbT[32 + col][quad*8];
        const short8 bt3 = *(const short8*)&cbT[48 + col][quad*8];
        e0 = __builtin_amdgcn_mfma_f32_16x16x32_bf16(pa, bt0, e0, 0,0,0);
        e1 = __builtin_amdgcn_mfma_f32_16x16x32_bf16(pa, bt1, e1, 0,0,0);
        e2 = __builtin_amdgcn_mfma_f32_16x16x32_bf16(pa, bt2, e2, 0,0,0);
        e3 = __builtin_amdgcn_mfma_f32_16x16x32_bf16(pa, bt3, e3, 0,0,0);
    }

    // ---- epilogue ----
    // Z: butterfly sum of per-lane partials (identical in all 16 lanes after)
    #pragma unroll
    for (int mask = 1; mask < 16; mask <<= 1) {
        #pragma unroll
        for (int j = 0; j < 4; ++j) Zp[j] += __shfl_xor(Zp[j], mask);
    }
    // top-2 merge across the 16 lanes of this quad
    #pragma unroll
    for (int mask = 1; mask < 16; mask <<= 1) {
        #pragma unroll
        for (int j = 0; j < 4; ++j) {
            float od1 = __shfl_xor(d1[j], mask);
            float od2 = __shfl_xor(d2[j], mask);
            int   ok1 = __shfl_xor(k1[j], mask);
            int   ok2 = __shfl_xor(k2[j], mask);
            bool mf = (d1[j] < od1) || (d1[j] == od1 && k1[j] < ok1);
            float b1  = mf ? d1[j] : od1;  int bk1 = mf ? k1[j] : ok1;
            float c1  = mf ? od1 : d1[j];  int ck1 = mf ? ok1 : k1[j];
            float c2  = mf ? d2[j] : od2;  int ck2 = mf ? k2[j] : ok2;
            bool s1 = (c1 < c2) || (c1 == c2 && ck1 < ck2);
            d1[j] = b1; k1[j] = bk1;
            d2[j] = s1 ? c1 : c2; k2[j] = s1 ? ck1 : ck2;
        }
    }
    // exact f64 refinement for near-ties (err of split-bf16 dist ~1e-6 << 1e-2 margin)
    #pragma unroll
    for (int j = 0; j < 4; ++j) {
        if (d2[j] - d1[j] < 1e-2f) {
            const int t = quad*4 + j;
            const int row = rowbase + (t >> 1) + ((t & 1) << 16);
            const float* xr = x + (size_t)row * DIM;
            double sx2 = 0.0;
            for (int d = 0; d < DIM; ++d) sx2 = fma((double)xr[d], (double)xr[d], sx2);
            double dd[2]; int kk[2] = {k1[j], k2[j]};
            for (int c = 0; c < 2; ++c) {
                const float* crow = cb + (size_t)kk[c] * DIM;
                double dot = 0.0, c2s = 0.0;
                for (int d = 0; d < DIM; ++d) {
                    double cj = (double)crow[d];
                    c2s = fma(cj, cj, c2s);
                    dot = fma((double)xr[d], cj, dot);
                }
                dd[c] = sx2 + c2s - 2.0 * dot;
            }
            if (dd[1] < dd[0] || (dd[1] == dd[0] && k2[j] < k1[j])) k1[j] = k2[j];
        }
    }
    // stores
    #pragma unroll
    for (int j = 0; j < 4; ++j) {
        const int t = quad*4 + j;
        const int row = rowbase + (t >> 1) + ((t & 1) << 16);
        const float rZ = 1.0f / Zp[j];
        out_emb[(size_t)row * DIM +      col] = e0[j] * rZ;
        out_emb[(size_t)row * DIM + 16 + col] = e1[j] * rZ;
        out_emb[(size_t)row * DIM + 32 + col] = e2[j] * rZ;
        out_emb[(size_t)row * DIM + 48 + col] = e3[j] * rZ;
        if (col == 0) out_ids[row] = (float)k1[j];
    }
}

extern "C" void kernel_launch(void* const* d_in, const int* in_sizes, int n_in,
                              void* d_out, int out_size, void* d_ws, size_t ws_size,
                              hipStream_t stream) {
    const float* x    = (const float*)d_in[0];
    const float* cb   = (const float*)d_in[1];
    const float* temp = (const float*)d_in[2];
    float* sumc2      = (float*)d_ws;
    float* out_emb    = (float*)d_out;
    float* out_ids    = (float*)d_out + (size_t)N_ROWS * DIM;

    sumc2_kernel<<<(K_CODES + 255) / 256, 256, 0, stream>>>(cb, sumc2);
    quant_kernel<<<N_ROWS / 64, 256, 0, stream>>>(x, cb, temp, sumc2, out_emb, out_ids);
}

// Round 4
// 636.845 us; speedup vs baseline: 1.5943x; 1.0024x over previous
//
#include <hip/hip_runtime.h>
#include <stdint.h>

#define N_ROWS 131072
#define DIM 64
#define K_CODES 1024

typedef __attribute__((ext_vector_type(8))) short short8;
typedef __attribute__((ext_vector_type(4))) float float4v;

// ---------------- bf16 split helpers ----------------
__device__ __forceinline__ uint16_t f2bf(float f) {          // RTNE
    uint32_t u = __float_as_uint(f);
    u += 0x7fffu + ((u >> 16) & 1u);
    return (uint16_t)(u >> 16);
}
__device__ __forceinline__ float bf2f(uint16_t h) {
    return __uint_as_float(((uint32_t)h) << 16);
}

// ---------------- kernel 1: per-code squared norms into d_ws ----------------
__global__ __launch_bounds__(256) void sumc2_kernel(const float* __restrict__ cb,
                                                    float* __restrict__ sumc2) {
    int k = blockIdx.x * 256 + threadIdx.x;
    if (k < K_CODES) {
        const float* r = cb + k * DIM;
        float s = 0.f;
        #pragma unroll
        for (int j = 0; j < DIM; ++j) s = fmaf(r[j], r[j], s);
        sumc2[k] = s;
    }
}

// ---------------- threefry2x32 (JAX-compatible, key = (0,42)) ----------------
__device__ __forceinline__ uint32_t rotl32(uint32_t x, uint32_t r) {
    return (x << r) | (x >> (32u - r));
}
__device__ __forceinline__ void tf_round(uint32_t& x0, uint32_t& x1, uint32_t r) {
    x0 += x1; x1 = rotl32(x1, r); x1 ^= x0;
}
__device__ __forceinline__ void threefry2x32_k42(uint32_t c0, uint32_t c1,
                                                 uint32_t& o0, uint32_t& o1) {
    const uint32_t ks0 = 0u, ks1 = 42u, ks2 = 0x1BD11BDAu ^ 0u ^ 42u;
    uint32_t x0 = c0 + ks0, x1 = c1 + ks1;
    tf_round(x0,x1,13); tf_round(x0,x1,15); tf_round(x0,x1,26); tf_round(x0,x1,6);
    x0 += ks1; x1 += ks2 + 1u;
    tf_round(x0,x1,17); tf_round(x0,x1,29); tf_round(x0,x1,16); tf_round(x0,x1,24);
    x0 += ks2; x1 += ks0 + 2u;
    tf_round(x0,x1,13); tf_round(x0,x1,15); tf_round(x0,x1,26); tf_round(x0,x1,6);
    x0 += ks0; x1 += ks1 + 3u;
    tf_round(x0,x1,17); tf_round(x0,x1,29); tf_round(x0,x1,16); tf_round(x0,x1,24);
    x0 += ks1; x1 += ks2 + 4u;
    tf_round(x0,x1,13); tf_round(x0,x1,15); tf_round(x0,x1,26); tf_round(x0,x1,6);
    x0 += ks2; x1 += ks0 + 5u;
    o0 = x0; o1 = x1;
}

__device__ __forceinline__ float gumbel_from_bits(uint32_t bits) {
    uint32_t fb = (bits >> 9) | 0x3f800000u;
    float f = __uint_as_float(fb) - 1.0f;
    float u = fmaxf(1.17549435e-38f, f);
    float w = u - 1.0f;
    float p = fmaf(w, 0.2f, -0.25f);
    p = fmaf(w, p, 0.33333333333f);
    p = fmaf(w, p, -0.5f);
    p = fmaf(w, p, 1.0f);
    float v_poly = -(w * p);
    float v_log  = -__logf(u);
    float v = (u > 0.9375f) ? v_poly : v_log;
    return -__logf(v);
}

__device__ __forceinline__ void top2_ins(float d, int k, float& d1, int& k1, float& d2, int& k2) {
    if (d < d1)      { d2 = d1; k2 = k1; d1 = d; k1 = k; }
    else if (d < d2) { d2 = d; k2 = k; }
}

// ---------------- kernel 2: flash-style fused MFMA quantizer ----------------
// LDS arena (19456 B), two overlaid epochs:
//   epoch A (init only):  xhi[4][16][72] @0, xlo @9216, xpart[4][16][4] @18432
//   epoch B (main loop):  cbhi[32][72] @0, cblo @4608, cbT[64][40] @9216,
//                         pbuf[4][16][40] @14336
// Strides: 72 halves (36 words: 2-way free), 40 halves (20 words: 2-way free);
// all row bases 16B-aligned for ds_read_b128.
__global__ __launch_bounds__(256) __attribute__((amdgpu_waves_per_eu(4, 4)))
void quant_kernel(
    const float* __restrict__ x, const float* __restrict__ cb,
    const float* __restrict__ temp, const float* __restrict__ sumc2g,
    float* __restrict__ out_emb, float* __restrict__ out_ids)
{
    __shared__ __align__(16) char smem[19456];
    uint16_t* const xhiP   = (uint16_t*)smem;            // [4][16][72]
    uint16_t* const xloP   = (uint16_t*)(smem + 9216);   // [4][16][72]
    float*    const xpartP = (float*)   (smem + 18432);  // [4][16][4]
    uint16_t* const cbhiP  = (uint16_t*)smem;            // [32][72]
    uint16_t* const cbloP  = (uint16_t*)(smem + 4608);   // [32][72]
    uint16_t* const cbTP   = (uint16_t*)(smem + 9216);   // [64][40]
    uint16_t* const pbufP  = (uint16_t*)(smem + 14336);  // [4][16][40]

    const int tid  = threadIdx.x;
    const int wave = tid >> 6;
    const int lane = tid & 63;
    const int quad = lane >> 4;
    const int col  = lane & 15;
    const float invT = 1.0f / temp[0];
    const int rowbase = blockIdx.x * 32 + wave * 8;      // low-row base for this wave

    // ---- epoch A: stage X tile + sumx2 partials ----
    {
        const int s = tid >> 2, w = s >> 4, t = s & 15, dq = tid & 3;
        const int row = blockIdx.x * 32 + w * 8 + (t >> 1) + ((t & 1) << 16);
        const float4* src = reinterpret_cast<const float4*>(x + (size_t)row * DIM + dq * 16);
        float v[16];
        #pragma unroll
        for (int i = 0; i < 4; ++i) {
            float4 f4 = src[i];
            v[4*i+0]=f4.x; v[4*i+1]=f4.y; v[4*i+2]=f4.z; v[4*i+3]=f4.w;
        }
        float ps = 0.f;
        short8 hv0, hv1, lv0, lv1;
        #pragma unroll
        for (int e = 0; e < 16; ++e) {
            ps = fmaf(v[e], v[e], ps);
            uint16_t h = f2bf(v[e]);
            uint16_t l = f2bf(v[e] - bf2f(h));
            if (e < 8) { hv0[e]   = (short)h; lv0[e]   = (short)l; }
            else       { hv1[e-8] = (short)h; lv1[e-8] = (short)l; }
        }
        const int rb = (w*16 + t)*72;
        *(short8*)&xhiP[rb + dq*16]     = hv0;
        *(short8*)&xhiP[rb + dq*16 + 8] = hv1;
        *(short8*)&xloP[rb + dq*16]     = lv0;
        *(short8*)&xloP[rb + dq*16 + 8] = lv1;
        xpartP[(w*16 + t)*4 + dq] = ps;
    }
    __syncthreads();

    // A-frags (cached in VGPRs for whole kernel): A[m=col][k=quad*8+j]
    const int arb = (wave*16 + col)*72;
    const short8 ahi0 = *(const short8*)&xhiP[arb + quad*8];
    const short8 ahi1 = *(const short8*)&xhiP[arb + 32 + quad*8];
    const short8 alo0 = *(const short8*)&xloP[arb + quad*8];
    const short8 alo1 = *(const short8*)&xloP[arb + 32 + quad*8];

    float sxr[4];
    #pragma unroll
    for (int j = 0; j < 4; ++j) {
        const float* xp = &xpartP[(wave*16 + quad*4 + j)*4];
        sxr[j] = (xp[0] + xp[1]) + (xp[2] + xp[3]);
    }

    float m[4]  = {-3.0e38f, -3.0e38f, -3.0e38f, -3.0e38f};
    float Zp[4] = {0.f, 0.f, 0.f, 0.f};
    float4v e0 = {0,0,0,0}, e1 = {0,0,0,0}, e2 = {0,0,0,0}, e3 = {0,0,0,0};
    float d1[4] = {3.4e38f,3.4e38f,3.4e38f,3.4e38f};
    float d2[4] = {3.4e38f,3.4e38f,3.4e38f,3.4e38f};
    int   k1[4] = {0,0,0,0}, k2[4] = {0,0,0,0};

    const uint32_t n0 = (uint32_t)(rowbase + 2*quad);    // < 65536 always
    const uint32_t n1 = n0 + 1u;

    for (int blk = 0; blk < 32; ++blk) {
        __syncthreads();                                 // prior reads done before overwrite
        const int kb = blk * 32;
        // ---- epoch B staging: 32 codes x 64 dims, hi/lo + transposed-hi ----
        {
            const int code = tid & 31, db = (tid >> 5) * 8;
            const float4* src = reinterpret_cast<const float4*>(cb + (size_t)(kb + code) * DIM + db);
            float4 a = src[0], b = src[1];
            float v[8] = {a.x,a.y,a.z,a.w,b.x,b.y,b.z,b.w};
            short8 hv, lv;
            uint16_t hh[8];
            #pragma unroll
            for (int e = 0; e < 8; ++e) {
                uint16_t h = f2bf(v[e]);
                uint16_t l = f2bf(v[e] - bf2f(h));
                hh[e] = h; hv[e] = (short)h; lv[e] = (short)l;
            }
            *(short8*)&cbhiP[code*72 + db] = hv;
            *(short8*)&cbloP[code*72 + db] = lv;
            #pragma unroll
            for (int e = 0; e < 8; ++e) cbTP[(db + e)*40 + code] = hh[e];
        }
        __syncthreads();

        // ---- GEMM1: S = X . CB^T  (split-bf16, 3 passes, 2 col-chunks) ----
        float4v S0 = {0,0,0,0}, S1 = {0,0,0,0};
        {
            const int rb0 = col*72;
            const short8 bh0 = *(const short8*)&cbhiP[rb0 + quad*8];
            const short8 bh1 = *(const short8*)&cbhiP[rb0 + 32 + quad*8];
            const short8 bl0 = *(const short8*)&cbloP[rb0 + quad*8];
            const short8 bl1 = *(const short8*)&cbloP[rb0 + 32 + quad*8];
            S0 = __builtin_amdgcn_mfma_f32_16x16x32_bf16(ahi0, bh0, S0, 0,0,0);
            S0 = __builtin_amdgcn_mfma_f32_16x16x32_bf16(ahi1, bh1, S0, 0,0,0);
            S0 = __builtin_amdgcn_mfma_f32_16x16x32_bf16(ahi0, bl0, S0, 0,0,0);
            S0 = __builtin_amdgcn_mfma_f32_16x16x32_bf16(ahi1, bl1, S0, 0,0,0);
            S0 = __builtin_amdgcn_mfma_f32_16x16x32_bf16(alo0, bh0, S0, 0,0,0);
            S0 = __builtin_amdgcn_mfma_f32_16x16x32_bf16(alo1, bh1, S0, 0,0,0);
        }
        {
            const int rb1 = (16 + col)*72;
            const short8 bh0 = *(const short8*)&cbhiP[rb1 + quad*8];
            const short8 bh1 = *(const short8*)&cbhiP[rb1 + 32 + quad*8];
            const short8 bl0 = *(const short8*)&cbloP[rb1 + quad*8];
            const short8 bl1 = *(const short8*)&cbloP[rb1 + 32 + quad*8];
            S1 = __builtin_amdgcn_mfma_f32_16x16x32_bf16(ahi0, bh0, S1, 0,0,0);
            S1 = __builtin_amdgcn_mfma_f32_16x16x32_bf16(ahi1, bh1, S1, 0,0,0);
            S1 = __builtin_amdgcn_mfma_f32_16x16x32_bf16(ahi0, bl0, S1, 0,0,0);
            S1 = __builtin_amdgcn_mfma_f32_16x16x32_bf16(ahi1, bl1, S1, 0,0,0);
            S1 = __builtin_amdgcn_mfma_f32_16x16x32_bf16(alo0, bh0, S1, 0,0,0);
            S1 = __builtin_amdgcn_mfma_f32_16x16x32_bf16(alo1, bh1, S1, 0,0,0);
        }

        // ---- gumbels (paired threefry: 2 calls serve 4 regs) ----
        const int kc0 = kb + col, kc1 = kb + 16 + col;
        float g0[4], g1[4];
        {
            uint32_t o0, o1, c;
            c = n0 * 1024u + (uint32_t)kc0;
            threefry2x32_k42(c, c + (1u << 26), o0, o1);
            g0[0] = gumbel_from_bits(o0); g0[1] = gumbel_from_bits(o1);
            c = n1 * 1024u + (uint32_t)kc0;
            threefry2x32_k42(c, c + (1u << 26), o0, o1);
            g0[2] = gumbel_from_bits(o0); g0[3] = gumbel_from_bits(o1);
            c = n0 * 1024u + (uint32_t)kc1;
            threefry2x32_k42(c, c + (1u << 26), o0, o1);
            g1[0] = gumbel_from_bits(o0); g1[1] = gumbel_from_bits(o1);
            c = n1 * 1024u + (uint32_t)kc1;
            threefry2x32_k42(c, c + (1u << 26), o0, o1);
            g1[2] = gumbel_from_bits(o0); g1[3] = gumbel_from_bits(o1);
        }

        const float sc0 = sumc2g[kc0], sc1 = sumc2g[kc1];
        float l0[4], l1[4], mn[4];
        #pragma unroll
        for (int j = 0; j < 4; ++j) {
            float dist0 = (sxr[j] + sc0) - 2.0f * S0[j];
            float dist1 = (sxr[j] + sc1) - 2.0f * S1[j];
            top2_ins(dist0, kc0, d1[j], k1[j], d2[j], k2[j]);
            top2_ins(dist1, kc1, d1[j], k1[j], d2[j], k2[j]);
            l0[j] = (g0[j] - dist0) * invT;
            l1[j] = (g1[j] - dist1) * invT;
            mn[j] = fmaxf(m[j], fmaxf(l0[j], l1[j]));
        }
        #pragma unroll
        for (int mask = 1; mask < 16; mask <<= 1) {
            #pragma unroll
            for (int j = 0; j < 4; ++j) mn[j] = fmaxf(mn[j], __shfl_xor(mn[j], mask));
        }
        float4v av;
        #pragma unroll
        for (int j = 0; j < 4; ++j) {
            float alpha = __expf(m[j] - mn[j]);
            m[j] = mn[j];
            av[j] = alpha;
            float p0 = __expf(l0[j] - mn[j]);
            float p1 = __expf(l1[j] - mn[j]);
            Zp[j] = fmaf(Zp[j], alpha, p0 + p1);
            pbufP[(wave*16 + quad*4 + j)*40 + col]      = f2bf(p0);
            pbufP[(wave*16 + quad*4 + j)*40 + 16 + col] = f2bf(p1);
        }
        e0 *= av; e1 *= av; e2 *= av; e3 *= av;
        __syncthreads();                                 // pbuf visible (cross-lane)

        // ---- GEMM2: emb += P . CB  (A=P[t][code], B=cbT[dim][code]) ----
        const short8 pa  = *(const short8*)&pbufP[(wave*16 + col)*40 + quad*8];
        const short8 bt0 = *(const short8*)&cbTP[ col      *40 + quad*8];
        const short8 bt1 = *(const short8*)&cbTP[(16 + col)*40 + quad*8];
        const short8 bt2 = *(const short8*)&cbTP[(32 + col)*40 + quad*8];
        const short8 bt3 = *(const short8*)&cbTP[(48 + col)*40 + quad*8];
        e0 = __builtin_amdgcn_mfma_f32_16x16x32_bf16(pa, bt0, e0, 0,0,0);
        e1 = __builtin_amdgcn_mfma_f32_16x16x32_bf16(pa, bt1, e1, 0,0,0);
        e2 = __builtin_amdgcn_mfma_f32_16x16x32_bf16(pa, bt2, e2, 0,0,0);
        e3 = __builtin_amdgcn_mfma_f32_16x16x32_bf16(pa, bt3, e3, 0,0,0);
    }

    // ---- epilogue ----
    #pragma unroll
    for (int mask = 1; mask < 16; mask <<= 1) {
        #pragma unroll
        for (int j = 0; j < 4; ++j) Zp[j] += __shfl_xor(Zp[j], mask);
    }
    #pragma unroll
    for (int mask = 1; mask < 16; mask <<= 1) {
        #pragma unroll
        for (int j = 0; j < 4; ++j) {
            float od1 = __shfl_xor(d1[j], mask);
            float od2 = __shfl_xor(d2[j], mask);
            int   ok1 = __shfl_xor(k1[j], mask);
            int   ok2 = __shfl_xor(k2[j], mask);
            bool mf = (d1[j] < od1) || (d1[j] == od1 && k1[j] < ok1);
            float b1  = mf ? d1[j] : od1;  int bk1 = mf ? k1[j] : ok1;
            float c1  = mf ? od1 : d1[j];  int ck1 = mf ? ok1 : k1[j];
            float c2  = mf ? d2[j] : od2;  int ck2 = mf ? k2[j] : ok2;
            bool s1 = (c1 < c2) || (c1 == c2 && ck1 < ck2);
            d1[j] = b1; k1[j] = bk1;
            d2[j] = s1 ? c1 : c2; k2[j] = s1 ? ck1 : ck2;
        }
    }
    // exact f64 refinement for near-ties (split-bf16 dist err ~1e-6 << 1e-2 margin)
    #pragma unroll
    for (int j = 0; j < 4; ++j) {
        if (d2[j] - d1[j] < 1e-2f) {
            const int t = quad*4 + j;
            const int row = rowbase + (t >> 1) + ((t & 1) << 16);
            const float* xr = x + (size_t)row * DIM;
            double sx2 = 0.0;
            for (int d = 0; d < DIM; ++d) sx2 = fma((double)xr[d], (double)xr[d], sx2);
            double dd[2]; int kk[2] = {k1[j], k2[j]};
            for (int c = 0; c < 2; ++c) {
                const float* crow = cb + (size_t)kk[c] * DIM;
                double dot = 0.0, c2s = 0.0;
                for (int d = 0; d < DIM; ++d) {
                    double cj = (double)crow[d];
                    c2s = fma(cj, cj, c2s);
                    dot = fma((double)xr[d], cj, dot);
                }
                dd[c] = sx2 + c2s - 2.0 * dot;
            }
            if (dd[1] < dd[0] || (dd[1] == dd[0] && k2[j] < k1[j])) k1[j] = k2[j];
        }
    }
    #pragma unroll
    for (int j = 0; j < 4; ++j) {
        const int t = quad*4 + j;
        const int row = rowbase + (t >> 1) + ((t & 1) << 16);
        const float rZ = 1.0f / Zp[j];
        out_emb[(size_t)row * DIM +      col] = e0[j] * rZ;
        out_emb[(size_t)row * DIM + 16 + col] = e1[j] * rZ;
        out_emb[(size_t)row * DIM + 32 + col] = e2[j] * rZ;
        out_emb[(size_t)row * DIM + 48 + col] = e3[j] * rZ;
        if (col == 0) out_ids[row] = (float)k1[j];
    }
}

extern "C" void kernel_launch(void* const* d_in, const int* in_sizes, int n_in,
                              void* d_out, int out_size, void* d_ws, size_t ws_size,
                              hipStream_t stream) {
    const float* x    = (const float*)d_in[0];
    const float* cb   = (const float*)d_in[1];
    const float* temp = (const float*)d_in[2];
    float* sumc2      = (float*)d_ws;
    float* out_emb    = (float*)d_out;
    float* out_ids    = (float*)d_out + (size_t)N_ROWS * DIM;

    sumc2_kernel<<<(K_CODES + 255) / 256, 256, 0, stream>>>(cb, sumc2);
    quant_kernel<<<N_ROWS / 64, 256, 0, stream>>>(x, cb, temp, sumc2, out_emb, out_ids);
}